// Round 4
// baseline (592.465 us; speedup 1.0000x reference)
//
#include <hip/hip_runtime.h>
#include <hip/hip_bf16.h>

#define GN 20000          // nodes
#define GE 320000         // edges (without self loops)
#define GETOT (GE + GN)   // edges + self loops
#define GH 4              // heads

typedef __attribute__((ext_vector_type(8))) short bf16x8;   // 8 bf16 = 4 VGPR
typedef __attribute__((ext_vector_type(4))) float f32x4;

// ---------------------------------------------------------------------------
// edge_index dtype detection (int64 vs x64-disabled int32)
// ---------------------------------------------------------------------------
__global__ void detect_dtype_kernel(const void* __restrict__ ei, int* __restrict__ flag) {
    if (threadIdx.x == 0 && blockIdx.x == 0) {
        const long long* p = (const long long*)ei;
        int ok = 1;
        for (int i = 0; i < 16; ++i) {
            long long v = p[i];
            if (v < 0 || v >= GN) ok = 0;
        }
        *flag = ok;
    }
}

__device__ __forceinline__ int load_idx(const void* ei, int is64, long long pos) {
    if (is64) return (int)((const long long*)ei)[pos];
    return ((const int*)ei)[pos];
}

// ---------------------------------------------------------------------------
// CSR build
// ---------------------------------------------------------------------------
__global__ void hist_kernel(const void* __restrict__ ei, const int* __restrict__ flagp,
                            int* __restrict__ counts) {
    int e = blockIdx.x * blockDim.x + threadIdx.x;
    if (e >= GETOT) return;
    int d;
    if (e < GE) d = load_idx(ei, *flagp, (long long)GE + e);
    else        d = e - GE;
    atomicAdd(&counts[d], 1);
}

__global__ void scan_kernel(const int* __restrict__ counts, int* __restrict__ offsets,
                            int* __restrict__ cursor) {
    __shared__ int sh[1024];
    int tid = threadIdx.x;
    int carry = 0;
    for (int base = 0; base < GN; base += 1024) {
        int i = base + tid;
        int v = (i < GN) ? counts[i] : 0;
        sh[tid] = v;
        __syncthreads();
        for (int o = 1; o < 1024; o <<= 1) {
            int t = (tid >= o) ? sh[tid - o] : 0;
            __syncthreads();
            sh[tid] += t;
            __syncthreads();
        }
        int excl = carry + sh[tid] - v;
        if (i < GN) { offsets[i] = excl; cursor[i] = excl; }
        carry += sh[1023];
        __syncthreads();
    }
    if (tid == 0) offsets[GN] = carry;
}

__global__ void scatter_kernel(const void* __restrict__ ei, const int* __restrict__ flagp,
                               int* __restrict__ cursor, int* __restrict__ csr_src) {
    int e = blockIdx.x * blockDim.x + threadIdx.x;
    if (e >= GETOT) return;
    int s, d;
    if (e < GE) {
        int is64 = *flagp;
        s = load_idx(ei, is64, e);
        d = load_idx(ei, is64, (long long)GE + e);
    } else {
        s = d = e - GE;
    }
    int pos = atomicAdd(&cursor[d], 1);
    csr_src[pos] = s;
}

// ---------------------------------------------------------------------------
// hi/lo bf16 split
// ---------------------------------------------------------------------------
__device__ __forceinline__ void split2(float v, short& h, short& l) {
    __hip_bfloat16 hb = __float2bfloat16(v);
    float r = v - __bfloat162float(hb);
    __hip_bfloat16 lb = __float2bfloat16(r);
    h = *reinterpret_cast<short*>(&hb);
    l = *reinterpret_cast<short*>(&lb);
}

// W fp32 [K][N]  ->  Wt hi/lo bf16 [N][Kpad] (transposed, zero-padded K)
__global__ void convert_wt(const float* __restrict__ W,
                           __hip_bfloat16* __restrict__ thi,
                           __hip_bfloat16* __restrict__ tlo,
                           int K, int N, int Kpad) {
    __shared__ float tile[32][33];
    int kb = blockIdx.x * 32, nb = blockIdx.y * 32;
    for (int i = threadIdx.y; i < 32; i += 8) {
        int k = kb + i, n = nb + threadIdx.x;
        tile[i][threadIdx.x] = (k < K) ? W[(size_t)k * N + n] : 0.f;
    }
    __syncthreads();
    for (int i = threadIdx.y; i < 32; i += 8) {
        int n = nb + i, k = kb + threadIdx.x;
        float v = tile[threadIdx.x][i];
        short h, l;
        split2(v, h, l);
        *(short*)&thi[(size_t)n * Kpad + k] = h;
        *(short*)&tlo[(size_t)n * Kpad + k] = l;
    }
}

// ---------------------------------------------------------------------------
// LDS swizzle (proven rounds 2-3): phys = swz(logical); bijective GF(2) map.
// ---------------------------------------------------------------------------
__device__ __forceinline__ int swz(int a) { return a ^ (((a >> 6) & 7) << 4); }
__device__ __forceinline__ int invswz(int p) {
    int b8 = (p >> 8) & 1, b7 = (p >> 7) & 1;
    int a6 = ((p >> 6) & 1) ^ b8;
    int a5 = ((p >> 5) & 1) ^ b7;
    int a4 = ((p >> 4) & 1) ^ a6;
    return (p & ~0x70) | (a4 << 4) | (a5 << 5) | (a6 << 6);
}

#define GLDS16(gsrc, ldst) __builtin_amdgcn_global_load_lds( \
    (const __attribute__((address_space(1))) void*)(gsrc),   \
    (__attribute__((address_space(3))) void*)(ldst), 16, 0, 0)

// ---------------------------------------------------------------------------
// Fused GEMM:  C[M,N] = A_f32[M,K] @ W  via  Ah*Bh + Ah*Bl + Al*Bh
// BM=128, BN=64, BK=32, 4 waves (wave tile 64x32).
// A: reg-staged fp32->hi/lo split, 16B ds_write_b128 units (conflict-light).
// B: (W^T hi/lo, [N][Kpad] K-contiguous) via global_load_lds width-16.
// Grid: 1D, bijective XCD-chunked remap so a row-panel's col-blocks share L2.
// ---------------------------------------------------------------------------
template <int NC>
__global__ __launch_bounds__(256, 4) void gemm_fused(
        const float* __restrict__ A, int lda, int K,
        const __hip_bfloat16* __restrict__ Bhi, const __hip_bfloat16* __restrict__ Blo,
        int Kpad, float* __restrict__ C, int M, int N) {
    __shared__ char Ah_s[8192];   // 128 x 32 bf16
    __shared__ char Al_s[8192];
    __shared__ char Bh_s[4096];   // 64 x 32 bf16
    __shared__ char Bl_s[4096];
    const int tid = threadIdx.x;

    // bijective XCD-chunked remap (m204): work order row-major -> col-blocks
    // of one row-panel land on the same XCD for A-panel L2 reuse.
    const int nwg = gridDim.x;
    const int q = nwg >> 3, r = nwg & 7;
    const int xcd = blockIdx.x & 7, sub = blockIdx.x >> 3;
    const int orig = (xcd < r ? xcd * (q + 1) : r * (q + 1) + (xcd - r) * q) + sub;
    const int brow = (orig / NC) * 128;
    const int bcol = (orig % NC) * 64;

    const int lane = tid & 63;
    const int wid  = tid >> 6;
    const int wr   = wid >> 1, wc = wid & 1;

    // B staging map (one 256x16B pass per buffer)
    const int pB    = tid * 16;
    const int aB    = invswz(pB);
    const int skelB = (aB & 63) >> 1;     // bf16 elem offset in row
    const int srowB = bcol + (aB >> 6);   // always valid (N % 64 == 0)

    // A staging map: unit u (16B = 8 elems), 2 units/thread
    int arow[2], acol[2];
#pragma unroll
    for (int p = 0; p < 2; ++p) {
        int u = tid + p * 256;
        arow[p] = u >> 2;
        acol[p] = (u & 3) * 8;            // element col 0,8,16,24
    }

    // fragment read offsets (swizzled; proven conflict-free pattern)
    const int l4 = lane & 15, kg = lane >> 4;
    int aoff[4], boff[2];
#pragma unroll
    for (int m = 0; m < 4; ++m) aoff[m] = swz((wr * 64 + m * 16 + l4) * 64 + kg * 16);
#pragma unroll
    for (int n = 0; n < 2; ++n) boff[n] = swz((wc * 32 + n * 16 + l4) * 64 + kg * 16);

    f32x4 acc[4][2];
#pragma unroll
    for (int m = 0; m < 4; ++m)
#pragma unroll
        for (int n = 0; n < 2; ++n) acc[m][n] = (f32x4)(0.f);

    for (int k0 = 0; k0 < Kpad; k0 += 32) {
        // A global loads (fp32, 2x 16B-unit = 4 float4), masked (K % 8 == 0)
        float4 av[2][2];
#pragma unroll
        for (int p = 0; p < 2; ++p) {
            int rg = brow + arow[p];
            int kk = k0 + acol[p];
            bool v = (rg < M) && (kk < K);
            const float* ap = A + (size_t)rg * lda + kk;
            av[p][0] = v ? *(const float4*)ap       : make_float4(0.f, 0.f, 0.f, 0.f);
            av[p][1] = v ? *(const float4*)(ap + 4) : make_float4(0.f, 0.f, 0.f, 0.f);
        }
        __syncthreads();
        // B async staging
        {
            size_t bo = (size_t)srowB * Kpad + k0 + skelB;
            GLDS16(Bhi + bo, Bh_s + pB);
            GLDS16(Blo + bo, Bl_s + pB);
        }
        // A split + swizzled 16B LDS writes
#pragma unroll
        for (int p = 0; p < 2; ++p) {
            short h[8], l[8];
            split2(av[p][0].x, h[0], l[0]); split2(av[p][0].y, h[1], l[1]);
            split2(av[p][0].z, h[2], l[2]); split2(av[p][0].w, h[3], l[3]);
            split2(av[p][1].x, h[4], l[4]); split2(av[p][1].y, h[5], l[5]);
            split2(av[p][1].z, h[6], l[6]); split2(av[p][1].w, h[7], l[7]);
            bf16x8 hv = {h[0], h[1], h[2], h[3], h[4], h[5], h[6], h[7]};
            bf16x8 lv = {l[0], l[1], l[2], l[3], l[4], l[5], l[6], l[7]};
            int la = swz(arow[p] * 64 + acol[p] * 2);
            *(bf16x8*)(Ah_s + la) = hv;
            *(bf16x8*)(Al_s + la) = lv;
        }
        __syncthreads();

        bf16x8 ah[4], al[4], bh[2], bl[2];
#pragma unroll
        for (int m = 0; m < 4; ++m) {
            ah[m] = *(const bf16x8*)(Ah_s + aoff[m]);
            al[m] = *(const bf16x8*)(Al_s + aoff[m]);
        }
#pragma unroll
        for (int n = 0; n < 2; ++n) {
            bh[n] = *(const bf16x8*)(Bh_s + boff[n]);
            bl[n] = *(const bf16x8*)(Bl_s + boff[n]);
        }
#pragma unroll
        for (int m = 0; m < 4; ++m)
#pragma unroll
            for (int n = 0; n < 2; ++n) {
                acc[m][n] = __builtin_amdgcn_mfma_f32_16x16x32_bf16(ah[m], bh[n], acc[m][n], 0, 0, 0);
                acc[m][n] = __builtin_amdgcn_mfma_f32_16x16x32_bf16(ah[m], bl[n], acc[m][n], 0, 0, 0);
                acc[m][n] = __builtin_amdgcn_mfma_f32_16x16x32_bf16(al[m], bh[n], acc[m][n], 0, 0, 0);
            }
    }

    // epilogue: D col = lane&15, row = (lane>>4)*4 + r
#pragma unroll
    for (int m = 0; m < 4; ++m) {
        int gr0 = brow + wr * 64 + m * 16 + (lane >> 4) * 4;
#pragma unroll
        for (int n = 0; n < 2; ++n) {
            int gc = bcol + wc * 32 + n * 16 + l4;
#pragma unroll
            for (int rr = 0; rr < 4; ++rr) {
                int gr = gr0 + rr;
                if (gr < M) C[(size_t)gr * N + gc] = acc[m][n][rr];
            }
        }
    }
}

// ---------------------------------------------------------------------------
// a_s / a_d per-node logits
// ---------------------------------------------------------------------------
__global__ void att_sd_kernel(const float* __restrict__ hfeat,
                              const float* __restrict__ att_s,
                              const float* __restrict__ att_d,
                              float* __restrict__ a_s, float* __restrict__ a_d,
                              int C) {
    int wid  = (blockIdx.x * blockDim.x + threadIdx.x) >> 6;
    int lane = threadIdx.x & 63;
    if (wid >= GN) return;
#pragma unroll
    for (int h = 0; h < GH; ++h) {
        float ss = 0.f, sd = 0.f;
        for (int cc = lane; cc < C; cc += 64) {
            float v = hfeat[(size_t)wid * GH * C + h * C + cc];
            ss += v * att_s[h * C + cc];
            sd += v * att_d[h * C + cc];
        }
#pragma unroll
        for (int o = 32; o; o >>= 1) {
            ss += __shfl_xor(ss, o);
            sd += __shfl_xor(sd, o);
        }
        if (lane == 0) { a_s[wid * GH + h] = ss; a_d[wid * GH + h] = sd; }
    }
}

// ---------------------------------------------------------------------------
// Per-node softmax + aggregation.  BLOCK = HC/2 threads, float2 per thread.
// 4-edge-unrolled gather for memory-level parallelism.
// ---------------------------------------------------------------------------
template <int C, bool FINAL, int BLOCK>
__global__ __launch_bounds__(BLOCK) void gat_aggregate(
        const float* __restrict__ hfeat,
        const float* __restrict__ a_s,
        const float* __restrict__ a_d,
        const int* __restrict__ offsets,
        const int* __restrict__ csr_src,
        const float* __restrict__ bias,
        float* __restrict__ out) {
    constexpr int HC = GH * C;
    static_assert(BLOCK == HC / 2, "one float2 per thread");
    const int n     = blockIdx.x;
    const int tid   = threadIdx.x;
    const int start = offsets[n];
    const int end   = offsets[n + 1];

    __shared__ float s_m[GH];
    __shared__ float s_den[GH];
    __shared__ int   s_src[64];
    __shared__ float s_al[GH][68];
    __shared__ float sacc[256];

    const float4 ad4 = *(const float4*)(a_d + n * GH);
    const float adh[GH] = {ad4.x, ad4.y, ad4.z, ad4.w};

    if (tid < 64) {
        float lmax[GH], lsum[GH];
#pragma unroll
        for (int h = 0; h < GH; ++h) lmax[h] = -1e30f;
        for (int e = start + tid; e < end; e += 64) {
            int s = csr_src[e];
            float4 as4 = *(const float4*)(a_s + s * GH);
            float l[GH] = {as4.x + adh[0], as4.y + adh[1], as4.z + adh[2], as4.w + adh[3]};
#pragma unroll
            for (int h = 0; h < GH; ++h) {
                float ll = l[h] > 0.f ? l[h] : 0.2f * l[h];
                lmax[h] = fmaxf(lmax[h], ll);
            }
        }
#pragma unroll
        for (int h = 0; h < GH; ++h)
#pragma unroll
            for (int o = 32; o; o >>= 1) lmax[h] = fmaxf(lmax[h], __shfl_xor(lmax[h], o));
#pragma unroll
        for (int h = 0; h < GH; ++h) lsum[h] = 0.f;
        for (int e = start + tid; e < end; e += 64) {
            int s = csr_src[e];
            float4 as4 = *(const float4*)(a_s + s * GH);
            float l[GH] = {as4.x + adh[0], as4.y + adh[1], as4.z + adh[2], as4.w + adh[3]};
#pragma unroll
            for (int h = 0; h < GH; ++h) {
                float ll = l[h] > 0.f ? l[h] : 0.2f * l[h];
                lsum[h] += __expf(ll - lmax[h]);
            }
        }
#pragma unroll
        for (int h = 0; h < GH; ++h)
#pragma unroll
            for (int o = 32; o; o >>= 1) lsum[h] += __shfl_xor(lsum[h], o);
        if (tid == 0) {
#pragma unroll
            for (int h = 0; h < GH; ++h) { s_m[h] = lmax[h]; s_den[h] = lsum[h]; }
        }
    }
    __syncthreads();

    float mm[GH], inv[GH];
#pragma unroll
    for (int h = 0; h < GH; ++h) { mm[h] = s_m[h]; inv[h] = 1.0f / s_den[h]; }

    const int hd = (2 * tid) / C;          // head of this thread's channel pair
    float2 acc = make_float2(0.f, 0.f);

    for (int e0 = start; e0 < end; e0 += 64) {
        __syncthreads();
        if (tid < 64) {
            bool vld = (e0 + tid) < end;
            int s = vld ? csr_src[e0 + tid] : n;
            s_src[tid] = s;
            float4 as4 = *(const float4*)(a_s + s * GH);
            float l[GH] = {as4.x + adh[0], as4.y + adh[1], as4.z + adh[2], as4.w + adh[3]};
#pragma unroll
            for (int h = 0; h < GH; ++h) {
                float ll = l[h] > 0.f ? l[h] : 0.2f * l[h];
                s_al[h][tid] = vld ? __expf(ll - mm[h]) * inv[h] : 0.f;
            }
        }
        __syncthreads();
        int cnt = end - e0; if (cnt > 64) cnt = 64;
        int cnt4 = (cnt + 3) & ~3;
        for (int i = 0; i < cnt4; i += 4) {
            int4   ss = *(const int4*)&s_src[i];
            float4 aa = *(const float4*)&s_al[hd][i];
            const float2* p0 = (const float2*)(hfeat + (size_t)ss.x * HC) + tid;
            const float2* p1 = (const float2*)(hfeat + (size_t)ss.y * HC) + tid;
            const float2* p2 = (const float2*)(hfeat + (size_t)ss.z * HC) + tid;
            const float2* p3 = (const float2*)(hfeat + (size_t)ss.w * HC) + tid;
            float2 v0 = *p0, v1 = *p1, v2 = *p2, v3 = *p3;
            acc.x = fmaf(aa.x, v0.x, acc.x); acc.y = fmaf(aa.x, v0.y, acc.y);
            acc.x = fmaf(aa.y, v1.x, acc.x); acc.y = fmaf(aa.y, v1.y, acc.y);
            acc.x = fmaf(aa.z, v2.x, acc.x); acc.y = fmaf(aa.z, v2.y, acc.y);
            acc.x = fmaf(aa.w, v3.x, acc.x); acc.y = fmaf(aa.w, v3.y, acc.y);
        }
    }

    if (!FINAL) {
        float2 b2 = *(const float2*)(bias + 2 * tid);
        float vx = acc.x + b2.x, vy = acc.y + b2.y;
        vx = vx > 0.f ? vx : expm1f(vx);
        vy = vy > 0.f ? vy : expm1f(vy);
        *(float2*)(out + (size_t)n * HC + 2 * tid) = make_float2(vx, vy);
    } else {
        sacc[2 * tid]     = acc.x;
        sacc[2 * tid + 1] = acc.y;
        __syncthreads();
        if (tid < C) {
            float v = 0.f;
#pragma unroll
            for (int h = 0; h < GH; ++h) v += sacc[h * C + tid];
            out[(size_t)n * C + tid] = v * (1.0f / GH) + bias[tid];
        }
    }
}

// ---------------------------------------------------------------------------
extern "C" void kernel_launch(void* const* d_in, const int* in_sizes, int n_in,
                              void* d_out, int out_size, void* d_ws, size_t ws_size,
                              hipStream_t stream) {
    const float* x  = (const float*)d_in[0];
    const void*  ei = d_in[1];
    const float* W[4]  = {(const float*)d_in[2],  (const float*)d_in[6],
                          (const float*)d_in[10], (const float*)d_in[14]};
    const float* AS[4] = {(const float*)d_in[3],  (const float*)d_in[7],
                          (const float*)d_in[11], (const float*)d_in[15]};
    const float* AD[4] = {(const float*)d_in[4],  (const float*)d_in[8],
                          (const float*)d_in[12], (const float*)d_in[16]};
    const float* BI[4] = {(const float*)d_in[5],  (const float*)d_in[9],
                          (const float*)d_in[13], (const float*)d_in[17]};

    char*  w   = (char*)d_ws;
    size_t off = 0;
    auto alloc = [&](size_t b) -> char* {
        char* p = w + off;
        off += (b + 255) & ~(size_t)255;
        return p;
    };
    int*   flag    = (int*)alloc(4);
    int*   counts  = (int*)alloc((GN + 1) * sizeof(int));
    int*   offsets = (int*)alloc((GN + 1) * sizeof(int));
    int*   cursor  = (int*)alloc(GN * sizeof(int));
    int*   csr_src = (int*)alloc((size_t)GETOT * sizeof(int));
    float* a_s     = (float*)alloc((size_t)GN * GH * sizeof(float));
    float* a_d     = (float*)alloc((size_t)GN * GH * sizeof(float));
    float* hbuf    = (float*)alloc((size_t)GN * 512 * sizeof(float));     // 41 MB (GEMM out)
    float* obuf    = (float*)alloc((size_t)GN * 512 * sizeof(float));     // 41 MB (agg out)
    __hip_bfloat16* wthi = (__hip_bfloat16*)alloc((size_t)512 * 2016 * 2); // 2.06 MB
    __hip_bfloat16* wtlo = (__hip_bfloat16*)alloc((size_t)512 * 2016 * 2); // 2.06 MB
    (void)in_sizes; (void)n_in; (void)out_size; (void)ws_size;

    // ---- CSR by destination (layer-invariant) ----
    detect_dtype_kernel<<<1, 64, 0, stream>>>(ei, flag);
    hipMemsetAsync(counts, 0, (GN + 1) * sizeof(int), stream);
    int eblocks = (GETOT + 255) / 256;
    hist_kernel<<<eblocks, 256, 0, stream>>>(ei, flag, counts);
    scan_kernel<<<1, 1024, 0, stream>>>(counts, offsets, cursor);
    scatter_kernel<<<eblocks, 256, 0, stream>>>(ei, flag, cursor, csr_src);

    const dim3 tb(32, 8);
    const int NR = (GN + 127) / 128;   // 157 row blocks

    // ---- layer 0: 2000 -> 4x128 concat, ELU ----
    convert_wt<<<dim3(2016 / 32, 512 / 32), tb, 0, stream>>>(W[0], wthi, wtlo, 2000, 512, 2016);
    gemm_fused<8><<<NR * 8, 256, 0, stream>>>(x, 2000, 2000, wthi, wtlo, 2016, hbuf, GN, 512);
    att_sd_kernel<<<(GN * 64) / 256, 256, 0, stream>>>(hbuf, AS[0], AD[0], a_s, a_d, 128);
    gat_aggregate<128, false, 256><<<GN, 256, 0, stream>>>(hbuf, a_s, a_d, offsets, csr_src,
                                                           BI[0], obuf);
    // ---- layer 1: 512 -> 4x64 concat, ELU ----
    convert_wt<<<dim3(512 / 32, 256 / 32), tb, 0, stream>>>(W[1], wthi, wtlo, 512, 256, 512);
    gemm_fused<4><<<NR * 4, 256, 0, stream>>>(obuf, 512, 512, wthi, wtlo, 512, hbuf, GN, 256);
    att_sd_kernel<<<(GN * 64) / 256, 256, 0, stream>>>(hbuf, AS[1], AD[1], a_s, a_d, 64);
    gat_aggregate<64, false, 128><<<GN, 128, 0, stream>>>(hbuf, a_s, a_d, offsets, csr_src,
                                                          BI[1], obuf);
    // ---- layer 2: 256 -> 4x32 concat, ELU ----
    convert_wt<<<dim3(256 / 32, 128 / 32), tb, 0, stream>>>(W[2], wthi, wtlo, 256, 128, 256);
    gemm_fused<2><<<NR * 2, 256, 0, stream>>>(obuf, 256, 256, wthi, wtlo, 256, hbuf, GN, 128);
    att_sd_kernel<<<(GN * 64) / 256, 256, 0, stream>>>(hbuf, AS[2], AD[2], a_s, a_d, 32);
    gat_aggregate<32, false, 64><<<GN, 64, 0, stream>>>(hbuf, a_s, a_d, offsets, csr_src,
                                                        BI[2], obuf);
    // ---- layer 3: 128 -> 4x64 mean, no ELU ----
    convert_wt<<<dim3(128 / 32, 256 / 32), tb, 0, stream>>>(W[3], wthi, wtlo, 128, 256, 128);
    gemm_fused<4><<<NR * 4, 256, 0, stream>>>(obuf, 128, 128, wthi, wtlo, 128, hbuf, GN, 256);
    att_sd_kernel<<<(GN * 64) / 256, 256, 0, stream>>>(hbuf, AS[3], AD[3], a_s, a_d, 64);
    gat_aggregate<64, true, 128><<<GN, 128, 0, stream>>>(hbuf, a_s, a_d, offsets, csr_src,
                                                         BI[3], (float*)d_out);
}